// Round 2
// baseline (509.894 us; speedup 1.0000x reference)
//
#include <hip/hip_runtime.h>

// ---------------------------------------------------------------------------
// CISSVAE forward on gfx950.
// R5: identical to R4 (resubmit — round 1 failed with "MI355X container
//     failed twice", an infra-side acquisition error; audit found no kernel
//     defect: glds tiling exact, 16B alignment holds, swizzle is an
//     involution with conflict-free read banks, barriers uniform).
// R4: tall wave tiles (128x64 per wave, 2 waves/block) + global_load_lds
//     staging. R3 was LDS-bound: 64x64 wave tiles + ds_write staging put
//     48KB/block/K-step on the LDS port vs 78 cyc of MFMA -> 20% MfmaUtil
//     ceiling (measured 20.0%). 128x64 tiles halve LDS ops per MFMA and
//     global_load_lds removes the reg->LDS write from the wave issue stream.
//     Swizzle moves to the per-lane GLOBAL source address (linear LDS dest,
//     same XOR involution on the read side).
// ---------------------------------------------------------------------------

#define DEVI __device__ __forceinline__

constexpr int B_    = 8192;
constexpr int DIN   = 2048;
constexpr int H0_   = 1024;
constexpr int H1_   = 512;
constexpr int LAT_  = 128;
constexpr int NC    = 8;

constexpr int BM = 128, BN = 128, BK = 32;
constexpr int TCAP   = 72;            // sum ceil(cnt_c/128) <= 64 + 7; divisible by 8
constexpr int BP_CAP = TCAP * BM;     // 9216 padded rows

#define MI_NTILES 8
#define MI_TILEC  16  // 72 ints: tile -> cluster

typedef __attribute__((ext_vector_type(8))) short bf16x8;
typedef __attribute__((ext_vector_type(4))) float f32x4;

DEVI unsigned short f2bf(float f) {      // RNE float -> bf16 bits
  union { float f; unsigned u; } a; a.f = f;
  unsigned r = a.u + 0x7fffu + ((a.u >> 16) & 1u);
  return (unsigned short)(r >> 16);
}

// async global->LDS, 16B per lane. LDS dest must be the wave-uniform base;
// HW writes lane i at base + i*16. Global src is per-lane (carries swizzle).
DEVI void glds16(const unsigned short* g, unsigned short* l) {
  __builtin_amdgcn_global_load_lds(
      (const __attribute__((address_space(1))) unsigned int*)g,
      (__attribute__((address_space(3))) unsigned int*)l,
      16, 0, 0);
}

// ---------------- workspace layout ----------------
constexpr size_t AL256(size_t x) { return (x + 255) & ~(size_t)255; }
constexpr size_t OFF_META = 0;                                       // 512 B
constexpr size_t OFF_PERM = 512;                                     // BP_CAP ints
constexpr size_t OFF_XG   = AL256(OFF_PERM + (size_t)BP_CAP * 4);    // u16 [BP_CAP][DIN]   (reused as d1)
constexpr size_t OFF_H0   = AL256(OFF_XG  + (size_t)BP_CAP * DIN * 2); // u16 [BP_CAP][H0]  (reused as d0)
constexpr size_t OFF_H1   = AL256(OFF_H0  + (size_t)BP_CAP * H0_ * 2); // u16 [BP_CAP][H1]  (reused as z)
constexpr size_t OFF_MLP  = AL256(OFF_H1  + (size_t)BP_CAP * H1_ * 2); // f32 [BP_CAP][256] mu|logvar
constexpr size_t OFF_BML  = AL256(OFF_MLP + (size_t)BP_CAP * 256 * 4); // f32 [256]
constexpr size_t OFF_WT0  = AL256(OFF_BML + 256 * 4);                  // u16 [NC][H0][DIN]
constexpr size_t OFF_WT1  = AL256(OFF_WT0 + (size_t)NC * DIN * H0_ * 2); // u16 [H1][H0]
constexpr size_t OFF_WML  = AL256(OFF_WT1 + (size_t)H0_ * H1_ * 2);      // u16 [256][H1]
constexpr size_t OFF_WD0  = AL256(OFF_WML + (size_t)256 * H1_ * 2);      // u16 [H1][LAT]
constexpr size_t OFF_WD1  = AL256(OFF_WD0 + (size_t)LAT_ * H1_ * 2);     // u16 [NC][H0][H1]
constexpr size_t OFF_WOUT = AL256(OFF_WD1 + (size_t)NC * H1_ * H0_ * 2); // u16 [DIN][H0]

// ---------------- setup (one block) ----------------
__global__ void setup_all(const int* __restrict__ labels, int* __restrict__ meta,
                          int* __restrict__ perm, const float* __restrict__ b_mu,
                          const float* __restrict__ b_lv, float* __restrict__ b_ml) {
  __shared__ int cnt[NC], base[NC];
  int t = threadIdx.x;
  if (t < NC) cnt[t] = 0;
  if (t < 256) b_ml[t] = (t < 128) ? b_mu[t] : b_lv[t - 128];
  __syncthreads();
  for (int i = t; i < B_; i += 1024) atomicAdd(&cnt[labels[i]], 1);
  for (int i = t; i < BP_CAP; i += 1024) perm[i] = -1;
  __syncthreads();
  if (t == 0) {
    int off = 0, nt = 0;
    for (int c = 0; c < NC; ++c) {
      base[c] = off;
      int k = (cnt[c] + BM - 1) >> 7;
      for (int j = 0; j < k; ++j) meta[MI_TILEC + nt + j] = c;
      nt += k;
      off += k << 7;
    }
    meta[MI_NTILES] = nt;
  }
  __syncthreads();
  if (t < NC) cnt[t] = base[t];        // reuse as cursors
  __syncthreads();
  for (int i = t; i < B_; i += 1024) {
    int pos = atomicAdd(&cnt[labels[i]], 1);
    perm[pos] = i;
  }
}

// ---------------- fused weight conversion: fp32 [nb][K][N] -> bf16 [nb][N][K]
// 64(k) x 32(n) tiles; writes are int4 (8 bf16 along K): 128 B per 8 threads.
struct SegDesc { const float* src; unsigned short* dst; int K, N, nb, tstart; };
struct SegTable { SegDesc s[7]; };

__global__ void convert_all(SegTable t) {
  __shared__ float tl[64][33];
  int tile = blockIdx.x;
  int si = 0;
#pragma unroll
  for (int i = 1; i < 7; ++i) si += (tile >= t.s[i].tstart) ? 1 : 0;
  const SegDesc sd = t.s[si];
  int local = tile - sd.tstart;
  int tpb = (sd.K >> 6) * (sd.N >> 5);
  int b = local / tpb, rem = local - b * tpb;
  int tk = rem / (sd.N >> 5), tn = rem - tk * (sd.N >> 5);
  const float* s = sd.src + (size_t)b * sd.K * sd.N;
  unsigned short* d = sd.dst + (size_t)b * sd.K * sd.N;
  int n0 = tn * 32, k0 = tk * 64;
  int tx = threadIdx.x, ty = threadIdx.y;          // (32, 8)
  for (int i = ty; i < 64; i += 8)
    tl[i][tx] = s[(size_t)(k0 + i) * sd.N + n0 + tx];
  __syncthreads();
  int id = ty * 32 + tx;
  int j = id >> 3;                 // 0..31 (n within tile)
  int kk = (id & 7) * 8;           // 0..56 (k within tile)
  unsigned short v[8];
#pragma unroll
  for (int q = 0; q < 8; ++q) v[q] = f2bf(tl[kk + q][j]);
  *(int4*)&d[(size_t)(n0 + j) * sd.K + k0 + kk] = *(int4*)v;
}

// gather + fp32->bf16 rows of x into permuted layout (zeros for padding rows)
__global__ void gather_x_kernel(const float* __restrict__ x, const int* __restrict__ perm,
                                unsigned short* __restrict__ xg) {
  int p = blockIdx.x;
  int c4 = blockIdx.y * 256 + threadIdx.x;   // 0..511 float4 per row
  int src = perm[p];
  float4 v = make_float4(0.f, 0.f, 0.f, 0.f);
  if (src >= 0) v = ((const float4*)(x + (size_t)src * DIN))[c4];
  ushort4 o;
  o.x = f2bf(v.x); o.y = f2bf(v.y); o.z = f2bf(v.z); o.w = f2bf(v.w);
  ((ushort4*)(xg + (size_t)p * DIN))[c4] = o;
}

// z = mu + eps*exp(0.5*logvar); scatter mu/logvar to output
__global__ void z_kernel(const float* __restrict__ mlp, const float* __restrict__ eps,
                         const int* __restrict__ perm, unsigned short* __restrict__ z,
                         float* __restrict__ out_mu, float* __restrict__ out_lv) {
  int p = blockIdx.x, j = threadIdx.x;
  int src = perm[p];
  float zz = 0.f;
  if (src >= 0) {
    float m = mlp[(size_t)p * 256 + j];
    float l = mlp[(size_t)p * 256 + 128 + j];
    zz = m + eps[(size_t)src * LAT_ + j] * expf(0.5f * l);
    out_mu[(size_t)src * LAT_ + j] = m;
    out_lv[(size_t)src * LAT_ + j] = l;
  }
  z[(size_t)p * LAT_ + j] = f2bf(zz);
}

// ---------------- GEMM: 2 waves x (128x64) wave tiles, glds staging --------
// C[M,N] = A[M,K] @ Bt[N,K]^T. LDS slot for (row r, 16B-chunk c) holds global
// chunk c ^ ((r>>1)&3) (self-inverse): glds writes LINEAR slots, the per-lane
// GLOBAL source address carries the permutation, fragment reads re-apply it.
// 2-phase: issue next-tile glds, compute current, __syncthreads (vmcnt drain).
template <int OUT_MODE, bool RELU, bool PCW, bool PCB>
__global__ __launch_bounds__(128, 2)
void gemm_kernel(const unsigned short* __restrict__ A,
                 const unsigned short* __restrict__ Bt,
                 const float* __restrict__ bias,
                 void* __restrict__ Cout,
                 const int* __restrict__ meta,
                 const int* __restrict__ perm,
                 int K, int N, int ldc) {
  // supertile swizzle: 8 consecutive tm share each tn sweep -> L2 reuse
  const int ntn = N >> 7;
  const int sup = 8 * ntn;
  const int gid = blockIdx.x;
  const int tm  = (gid / sup) * 8 + (gid & 7);
  const int tn  = (gid % sup) >> 3;
  if (tm >= meta[MI_NTILES]) return;

  int cluster = 0;
  if (PCW || PCB) cluster = meta[MI_TILEC + tm];
  const unsigned short* Bp = Bt + (PCW ? (size_t)cluster * (size_t)N * K : 0);
  const float* bb = bias + (PCB ? (size_t)cluster * N : 0);

  __shared__ alignas(16) unsigned short As[2][BM * BK];   // 8KB per buf
  __shared__ alignas(16) unsigned short Bs[2][BN * BK];   // 8KB per buf

  const int tid  = threadIdx.x;
  const int w    = tid >> 6, lane = tid & 63;
  const int fr   = lane & 15, quad = lane >> 4;

  // staging: 8 glds per wave (4 A + 4 B), each covers 64 slots (16 rows).
  // lane's slot s -> row r = s>>2, swizzled source chunk c = (s&3)^((r>>1)&3)
  const unsigned short* aP[4];
  const unsigned short* bP[4];
#pragma unroll
  for (int j = 0; j < 4; ++j) {
    int s = (w * 4 + j) * 64 + lane;
    int r = s >> 2;
    int c = (s & 3) ^ ((r >> 1) & 3);
    aP[j] = A  + (size_t)(tm * BM + r) * K + c * 8;
    bP[j] = Bp + (size_t)(tn * BN + r) * K + c * 8;
  }

  // fragment read offsets (elements): wave covers rows 0..127, cols w*64..+63
  int aro[8], bro[4];
#pragma unroll
  for (int i = 0; i < 8; ++i) {
    int R = i * 16 + fr;
    aro[i] = (R * 4 + (quad ^ ((R >> 1) & 3))) * 8;
  }
#pragma unroll
  for (int i = 0; i < 4; ++i) {
    int R = w * 64 + i * 16 + fr;
    bro[i] = (R * 4 + (quad ^ ((R >> 1) & 3))) * 8;
  }

  f32x4 acc[8][4] = {};

  auto stage = [&](int buf, int k0) {
#pragma unroll
    for (int j = 0; j < 4; ++j) {
      glds16(aP[j] + k0, &As[buf][(w * 4 + j) * 512]);
      glds16(bP[j] + k0, &Bs[buf][(w * 4 + j) * 512]);
    }
  };

  auto compute = [&](int buf) {
    bf16x8 af[8], bfr[4];
#pragma unroll
    for (int i = 0; i < 4; ++i) bfr[i] = *(const bf16x8*)&Bs[buf][bro[i]];
#pragma unroll
    for (int i = 0; i < 8; ++i) af[i]  = *(const bf16x8*)&As[buf][aro[i]];
#pragma unroll
    for (int mi = 0; mi < 8; ++mi)
#pragma unroll
      for (int ni = 0; ni < 4; ++ni)
        acc[mi][ni] = __builtin_amdgcn_mfma_f32_16x16x32_bf16(af[mi], bfr[ni], acc[mi][ni], 0, 0, 0);
  };

  // prologue: tile 0 -> LDS[0]
  stage(0, 0);
  __syncthreads();

  int cur = 0;
  for (int k0 = BK; k0 < K; k0 += BK) {
    stage(cur ^ 1, k0);      // loads stay in flight while we compute
    compute(cur);
    __syncthreads();         // drains vmcnt (glds landed) + readers done
    cur ^= 1;
  }
  compute(cur);

  // epilogue: D row = mi*16 + quad*4 + r (M), col = w*64 + ni*16 + fr (N)
  float bv[4];
#pragma unroll
  for (int ni = 0; ni < 4; ++ni) bv[ni] = bb[tn * BN + w * 64 + ni * 16 + fr];

#pragma unroll
  for (int mi = 0; mi < 8; ++mi) {
#pragma unroll
    for (int r = 0; r < 4; ++r) {
      int m = tm * BM + mi * 16 + quad * 4 + r;
      int orow = m;
      if (OUT_MODE == 2) orow = perm[m];
#pragma unroll
      for (int ni = 0; ni < 4; ++ni) {
        int n = tn * BN + w * 64 + ni * 16 + fr;
        float v = acc[mi][ni][r] + bv[ni];
        if (RELU) v = fmaxf(v, 0.f);
        if (OUT_MODE == 0) {
          ((unsigned short*)Cout)[(size_t)m * N + n] = f2bf(v);
        } else if (OUT_MODE == 1) {
          ((float*)Cout)[(size_t)m * N + n] = v;
        } else {
          if (orow >= 0) ((float*)Cout)[(size_t)orow * ldc + n] = v;
        }
      }
    }
  }
}

// ---------------- launch ----------------
extern "C" void kernel_launch(void* const* d_in, const int* in_sizes, int n_in,
                              void* d_out, int out_size, void* d_ws, size_t ws_size,
                              hipStream_t stream) {
  const float* x        = (const float*)d_in[0];
  const int*   labels   = (const int*)d_in[1];
  const float* eps      = (const float*)d_in[2];
  const float* W_enc0   = (const float*)d_in[3];
  const float* b_enc0   = (const float*)d_in[4];
  const float* W_enc1   = (const float*)d_in[5];
  const float* b_enc1   = (const float*)d_in[6];
  const float* W_mu     = (const float*)d_in[7];
  const float* b_mu     = (const float*)d_in[8];
  const float* W_logvar = (const float*)d_in[9];
  const float* b_logvar = (const float*)d_in[10];
  const float* W_dec0   = (const float*)d_in[11];
  const float* b_dec0   = (const float*)d_in[12];
  const float* W_dec1   = (const float*)d_in[13];
  const float* b_dec1   = (const float*)d_in[14];
  const float* W_out    = (const float*)d_in[15];
  const float* b_out    = (const float*)d_in[16];

  float* out_recon = (float*)d_out;
  float* out_mu    = out_recon + (size_t)B_ * DIN;
  float* out_lv    = out_mu + (size_t)B_ * LAT_;

  char* ws = (char*)d_ws;
  int* meta            = (int*)(ws + OFF_META);
  int* perm            = (int*)(ws + OFF_PERM);
  unsigned short* xg   = (unsigned short*)(ws + OFF_XG);
  unsigned short* h0   = (unsigned short*)(ws + OFF_H0);
  unsigned short* h1   = (unsigned short*)(ws + OFF_H1);
  float* mlp           = (float*)(ws + OFF_MLP);
  float* b_ml          = (float*)(ws + OFF_BML);
  unsigned short* Wt0  = (unsigned short*)(ws + OFF_WT0);
  unsigned short* Wt1  = (unsigned short*)(ws + OFF_WT1);
  unsigned short* Wml  = (unsigned short*)(ws + OFF_WML);
  unsigned short* Wd0  = (unsigned short*)(ws + OFF_WD0);
  unsigned short* Wd1  = (unsigned short*)(ws + OFF_WD1);
  unsigned short* Wout = (unsigned short*)(ws + OFF_WOUT);
  // buffer reuse (lifetimes disjoint):
  unsigned short* d1 = xg;   // [BP_CAP][H0]
  unsigned short* d0 = h0;   // [BP_CAP][H1]
  unsigned short* z  = h1;   // [BP_CAP][LAT]

  // fused conversion table (64k x 32n tiles)
  SegTable st;
  int ts = 0;
  auto seg = [&](int i, const float* s, unsigned short* d, int K, int N, int nb) {
    st.s[i] = SegDesc{s, d, K, N, nb, ts};
    ts += (K / 64) * (N / 32) * nb;
  };
  seg(0, W_enc0,   Wt0,                      DIN,  H0_,  NC);
  seg(1, W_enc1,   Wt1,                      H0_,  H1_,  1);
  seg(2, W_mu,     Wml,                      H1_,  LAT_, 1);
  seg(3, W_logvar, Wml + (size_t)LAT_ * H1_, H1_,  LAT_, 1);
  seg(4, W_dec0,   Wd0,                      LAT_, H1_,  1);
  seg(5, W_dec1,   Wd1,                      H1_,  H0_,  NC);
  seg(6, W_out,    Wout,                     H0_,  DIN,  1);

  setup_all<<<1, 1024, 0, stream>>>(labels, meta, perm, b_mu, b_logvar, b_ml);
  convert_all<<<ts, dim3(32, 8), 0, stream>>>(st);
  gather_x_kernel<<<dim3(BP_CAP, DIN / (256 * 4)), 256, 0, stream>>>(x, perm, xg);

  // enc0: [Bp,2048] @ Wt0[c][1024][2048] -> h0, relu
  gemm_kernel<0, true, true, true><<<TCAP * (H0_ / BN), 128, 0, stream>>>(
      xg, Wt0, b_enc0, h0, meta, perm, DIN, H0_, 0);
  // enc1: [Bp,1024] @ Wt1[512][1024] -> h1, relu
  gemm_kernel<0, true, false, false><<<TCAP * (H1_ / BN), 128, 0, stream>>>(
      h0, Wt1, b_enc1, h1, meta, perm, H0_, H1_, 0);
  // mu|logvar: [Bp,512] @ Wml[256][512] -> mlp (fp32)
  gemm_kernel<1, false, false, false><<<TCAP * (256 / BN), 128, 0, stream>>>(
      h1, Wml, b_ml, mlp, meta, perm, H1_, 256, 0);
  // reparameterize + scatter mu/logvar
  z_kernel<<<BP_CAP, 128, 0, stream>>>(mlp, eps, perm, z, out_mu, out_lv);
  // dec0: [Bp,128] @ Wd0[512][128] -> d0, relu
  gemm_kernel<0, true, false, false><<<TCAP * (H1_ / BN), 128, 0, stream>>>(
      z, Wd0, b_dec0, d0, meta, perm, LAT_, H1_, 0);
  // dec1: [Bp,512] @ Wd1[c][1024][512] -> d1, relu
  gemm_kernel<0, true, true, true><<<TCAP * (H0_ / BN), 128, 0, stream>>>(
      d0, Wd1, b_dec1, d1, meta, perm, H1_, H0_, 0);
  // out: [Bp,1024] @ Wout[2048][1024] -> scatter fp32 recon
  gemm_kernel<2, false, false, false><<<TCAP * (DIN / BN), 128, 0, stream>>>(
      d1, Wout, b_out, out_recon, meta, perm, H0_, DIN, DIN);

  (void)in_sizes; (void)n_in; (void)out_size; (void)ws_size;
}

// Round 3
// 421.224 us; speedup vs baseline: 1.2105x; 1.2105x over previous
//
#include <hip/hip_runtime.h>

// ---------------------------------------------------------------------------
// CISSVAE forward on gfx950.
// R6: revert to R3 structure (reg-staged GEMM, lgkm-only barrier, 256-thr
//     blocks) + 2-deep register pipeline. R4/R5 post-mortem: glds +
//     __syncthreads reintroduced the per-K-step vmcnt(0) drain and halved
//     wave count -> MfmaUtil 20->14.8, dur 69.9->96.7. R3's binder is load
//     LATENCY: ds_write of tile k+1 waits on globals issued only ~1 phase
//     earlier. R6 keeps TWO reg sets so every load is in flight ~2 full
//     phases before its counted-vmcnt wait; loop unrolled by 2 so all reg
//     sets / LDS buffer indices are compile-time (K/BK always even here).
// ---------------------------------------------------------------------------

#define DEVI __device__ __forceinline__

constexpr int B_    = 8192;
constexpr int DIN   = 2048;
constexpr int H0_   = 1024;
constexpr int H1_   = 512;
constexpr int LAT_  = 128;
constexpr int NC    = 8;

constexpr int BM = 128, BN = 128, BK = 32;
constexpr int TCAP   = 72;            // sum ceil(cnt_c/128) <= 64 + 7; divisible by 8
constexpr int BP_CAP = TCAP * BM;     // 9216 padded rows

#define MI_NTILES 8
#define MI_TILEC  16  // 72 ints: tile -> cluster

typedef __attribute__((ext_vector_type(8))) short bf16x8;
typedef __attribute__((ext_vector_type(4))) float f32x4;

// barrier that does NOT drain vmcnt: LDS ops only.
#define LDS_BARRIER() asm volatile("s_waitcnt lgkmcnt(0)\n\ts_barrier" ::: "memory")

DEVI unsigned short f2bf(float f) {      // RNE float -> bf16 bits
  union { float f; unsigned u; } a; a.f = f;
  unsigned r = a.u + 0x7fffu + ((a.u >> 16) & 1u);
  return (unsigned short)(r >> 16);
}

// ---------------- workspace layout ----------------
constexpr size_t AL256(size_t x) { return (x + 255) & ~(size_t)255; }
constexpr size_t OFF_META = 0;                                       // 512 B
constexpr size_t OFF_PERM = 512;                                     // BP_CAP ints
constexpr size_t OFF_XG   = AL256(OFF_PERM + (size_t)BP_CAP * 4);    // u16 [BP_CAP][DIN]   (reused as d1)
constexpr size_t OFF_H0   = AL256(OFF_XG  + (size_t)BP_CAP * DIN * 2); // u16 [BP_CAP][H0]  (reused as d0)
constexpr size_t OFF_H1   = AL256(OFF_H0  + (size_t)BP_CAP * H0_ * 2); // u16 [BP_CAP][H1]  (reused as z)
constexpr size_t OFF_MLP  = AL256(OFF_H1  + (size_t)BP_CAP * H1_ * 2); // f32 [BP_CAP][256] mu|logvar
constexpr size_t OFF_BML  = AL256(OFF_MLP + (size_t)BP_CAP * 256 * 4); // f32 [256]
constexpr size_t OFF_WT0  = AL256(OFF_BML + 256 * 4);                  // u16 [NC][H0][DIN]
constexpr size_t OFF_WT1  = AL256(OFF_WT0 + (size_t)NC * DIN * H0_ * 2); // u16 [H1][H0]
constexpr size_t OFF_WML  = AL256(OFF_WT1 + (size_t)H0_ * H1_ * 2);      // u16 [256][H1]
constexpr size_t OFF_WD0  = AL256(OFF_WML + (size_t)256 * H1_ * 2);      // u16 [H1][LAT]
constexpr size_t OFF_WD1  = AL256(OFF_WD0 + (size_t)LAT_ * H1_ * 2);     // u16 [NC][H0][H1]
constexpr size_t OFF_WOUT = AL256(OFF_WD1 + (size_t)NC * H1_ * H0_ * 2); // u16 [DIN][H0]

// ---------------- setup (one block) ----------------
__global__ void setup_all(const int* __restrict__ labels, int* __restrict__ meta,
                          int* __restrict__ perm, const float* __restrict__ b_mu,
                          const float* __restrict__ b_lv, float* __restrict__ b_ml) {
  __shared__ int cnt[NC], base[NC];
  int t = threadIdx.x;
  if (t < NC) cnt[t] = 0;
  if (t < 256) b_ml[t] = (t < 128) ? b_mu[t] : b_lv[t - 128];
  __syncthreads();
  for (int i = t; i < B_; i += 1024) atomicAdd(&cnt[labels[i]], 1);
  for (int i = t; i < BP_CAP; i += 1024) perm[i] = -1;
  __syncthreads();
  if (t == 0) {
    int off = 0, nt = 0;
    for (int c = 0; c < NC; ++c) {
      base[c] = off;
      int k = (cnt[c] + BM - 1) >> 7;
      for (int j = 0; j < k; ++j) meta[MI_TILEC + nt + j] = c;
      nt += k;
      off += k << 7;
    }
    meta[MI_NTILES] = nt;
  }
  __syncthreads();
  if (t < NC) cnt[t] = base[t];        // reuse as cursors
  __syncthreads();
  for (int i = t; i < B_; i += 1024) {
    int pos = atomicAdd(&cnt[labels[i]], 1);
    perm[pos] = i;
  }
}

// ---------------- fused weight conversion: fp32 [nb][K][N] -> bf16 [nb][N][K]
// 64(k) x 32(n) tiles; writes are int4 (8 bf16 along K): 128 B per 8 threads.
struct SegDesc { const float* src; unsigned short* dst; int K, N, nb, tstart; };
struct SegTable { SegDesc s[7]; };

__global__ void convert_all(SegTable t) {
  __shared__ float tl[64][33];
  int tile = blockIdx.x;
  int si = 0;
#pragma unroll
  for (int i = 1; i < 7; ++i) si += (tile >= t.s[i].tstart) ? 1 : 0;
  const SegDesc sd = t.s[si];
  int local = tile - sd.tstart;
  int tpb = (sd.K >> 6) * (sd.N >> 5);
  int b = local / tpb, rem = local - b * tpb;
  int tk = rem / (sd.N >> 5), tn = rem - tk * (sd.N >> 5);
  const float* s = sd.src + (size_t)b * sd.K * sd.N;
  unsigned short* d = sd.dst + (size_t)b * sd.K * sd.N;
  int n0 = tn * 32, k0 = tk * 64;
  int tx = threadIdx.x, ty = threadIdx.y;          // (32, 8)
  for (int i = ty; i < 64; i += 8)
    tl[i][tx] = s[(size_t)(k0 + i) * sd.N + n0 + tx];
  __syncthreads();
  int id = ty * 32 + tx;
  int j = id >> 3;                 // 0..31 (n within tile)
  int kk = (id & 7) * 8;           // 0..56 (k within tile)
  unsigned short v[8];
#pragma unroll
  for (int q = 0; q < 8; ++q) v[q] = f2bf(tl[kk + q][j]);
  *(int4*)&d[(size_t)(n0 + j) * sd.K + k0 + kk] = *(int4*)v;
}

// gather + fp32->bf16 rows of x into permuted layout (zeros for padding rows)
__global__ void gather_x_kernel(const float* __restrict__ x, const int* __restrict__ perm,
                                unsigned short* __restrict__ xg) {
  int p = blockIdx.x;
  int c4 = blockIdx.y * 256 + threadIdx.x;   // 0..511 float4 per row
  int src = perm[p];
  float4 v = make_float4(0.f, 0.f, 0.f, 0.f);
  if (src >= 0) v = ((const float4*)(x + (size_t)src * DIN))[c4];
  ushort4 o;
  o.x = f2bf(v.x); o.y = f2bf(v.y); o.z = f2bf(v.z); o.w = f2bf(v.w);
  ((ushort4*)(xg + (size_t)p * DIN))[c4] = o;
}

// z = mu + eps*exp(0.5*logvar); scatter mu/logvar to output
__global__ void z_kernel(const float* __restrict__ mlp, const float* __restrict__ eps,
                         const int* __restrict__ perm, unsigned short* __restrict__ z,
                         float* __restrict__ out_mu, float* __restrict__ out_lv) {
  int p = blockIdx.x, j = threadIdx.x;
  int src = perm[p];
  float zz = 0.f;
  if (src >= 0) {
    float m = mlp[(size_t)p * 256 + j];
    float l = mlp[(size_t)p * 256 + 128 + j];
    zz = m + eps[(size_t)src * LAT_ + j] * expf(0.5f * l);
    out_mu[(size_t)src * LAT_ + j] = m;
    out_lv[(size_t)src * LAT_ + j] = l;
  }
  z[(size_t)p * LAT_ + j] = f2bf(zz);
}

// ---------------- GEMM: reg-staged, 2-deep pipeline, lgkm-only barrier ----
// C[M,N] = A[M,K] @ Bt[N,K]^T. LDS slot for (row r, 16B-chunk c) is
// r*4 + (c ^ ((r>>1)&3)) (conflict-free b128 reads; staged by permuting each
// lane's SOURCE chunk). Phase i: compute LDS[i&1]; ds_write LDS[(i+1)&1]
// from reg set (i+1)&1 (loads issued ~2 phases ago -> counted vmcnt, no
// drain); re-issue that set for tile i+3; lgkm barrier. nt = K/BK is even
// for every layer here (64/32/16/4), so the unroll-by-2 pairing is exact.
template <int OUT_MODE, bool RELU, bool PCW, bool PCB>
__global__ __launch_bounds__(256, 2)
void gemm_kernel(const unsigned short* __restrict__ A,
                 const unsigned short* __restrict__ Bt,
                 const float* __restrict__ bias,
                 void* __restrict__ Cout,
                 const int* __restrict__ meta,
                 const int* __restrict__ perm,
                 int K, int N, int ldc) {
  // supertile swizzle: 8 consecutive tm share each tn sweep -> L2 reuse
  const int ntn = N >> 7;
  const int sup = 8 * ntn;
  const int gid = blockIdx.x;
  const int tm  = (gid / sup) * 8 + (gid & 7);
  const int tn  = (gid % sup) >> 3;
  if (tm >= meta[MI_NTILES]) return;

  int cluster = 0;
  if (PCW || PCB) cluster = meta[MI_TILEC + tm];
  const unsigned short* Bp = Bt + (PCW ? (size_t)cluster * (size_t)N * K : 0);
  const float* bb = bias + (PCB ? (size_t)cluster * N : 0);

  __shared__ alignas(16) unsigned short As[2][BM * BK];
  __shared__ alignas(16) unsigned short Bs[2][BN * BK];

  const int tid  = threadIdx.x;
  const int w    = tid >> 6, lane = tid & 63;
  const int fr   = lane & 15, quad = lane >> 4;
  const int wm   = (w >> 1) * 64, wn = (w & 1) * 64;

  // staging slots (16B each); global source chunk is XOR-swizzled
  const int s0 = (w * 2 + 0) * 64 + lane;
  const int s1 = (w * 2 + 1) * 64 + lane;
  const int r0 = s0 >> 2, r1 = s1 >> 2;
  const int c0 = (s0 & 3) ^ ((r0 >> 1) & 3);
  const int c1 = (s1 & 3) ^ ((r1 >> 1) & 3);
  const unsigned short* pa0 = A  + (size_t)(tm * BM + r0) * K + c0 * 8;
  const unsigned short* pa1 = A  + (size_t)(tm * BM + r1) * K + c1 * 8;
  const unsigned short* pb0 = Bp + (size_t)(tn * BN + r0) * K + c0 * 8;
  const unsigned short* pb1 = Bp + (size_t)(tn * BN + r1) * K + c1 * 8;
  const int l0 = s0 * 8, l1 = s1 * 8;  // element offsets in LDS

  // fragment read offsets (elements)
  int aro[4], bro[4];
#pragma unroll
  for (int i = 0; i < 4; ++i) {
    int R = wm + i * 16 + fr;
    aro[i] = (R * 4 + (quad ^ ((R >> 1) & 3))) * 8;
    R = wn + i * 16 + fr;
    bro[i] = (R * 4 + (quad ^ ((R >> 1) & 3))) * 8;
  }

  f32x4 acc[4][4] = {};

  auto compute = [&](int buf) {
    bf16x8 af[4], bfr[4];
#pragma unroll
    for (int i = 0; i < 4; ++i) af[i]  = *(const bf16x8*)&As[buf][aro[i]];
#pragma unroll
    for (int i = 0; i < 4; ++i) bfr[i] = *(const bf16x8*)&Bs[buf][bro[i]];
#pragma unroll
    for (int mi = 0; mi < 4; ++mi)
#pragma unroll
      for (int ni = 0; ni < 4; ++ni)
        acc[mi][ni] = __builtin_amdgcn_mfma_f32_16x16x32_bf16(af[mi], bfr[ni], acc[mi][ni], 0, 0, 0);
  };

  const int nt = K / BK;               // even: 64/32/16/4

  // two register staging sets (static names; never runtime-indexed)
  int4 a0A, a0B, b0A, b0B;             // set0
  int4 a1A, a1B, b1A, b1B;             // set1

  // prologue: set0 <- tile0; LDS[0] <- set0; set1 <- tile1; set0 <- tile2
  a0A = *(const int4*)(pa0);  a0B = *(const int4*)(pa1);
  b0A = *(const int4*)(pb0);  b0B = *(const int4*)(pb1);
  a1A = *(const int4*)(pa0 + BK);  a1B = *(const int4*)(pa1 + BK);
  b1A = *(const int4*)(pb0 + BK);  b1B = *(const int4*)(pb1 + BK);
  *(int4*)&As[0][l0] = a0A;  *(int4*)&As[0][l1] = a0B;   // waits vmcnt(4)
  *(int4*)&Bs[0][l0] = b0A;  *(int4*)&Bs[0][l1] = b0B;
  a0A = *(const int4*)(pa0 + 2 * BK);  a0B = *(const int4*)(pa1 + 2 * BK);
  b0A = *(const int4*)(pb0 + 2 * BK);  b0B = *(const int4*)(pb1 + 2 * BK);
  LDS_BARRIER();

  // phase 0: compute t0 (LDS0); write LDS1 <- set1 (t1); issue set1 <- t3
  compute(0);
  *(int4*)&As[1][l0] = a1A;  *(int4*)&As[1][l1] = a1B;
  *(int4*)&Bs[1][l0] = b1A;  *(int4*)&Bs[1][l1] = b1B;
  if (3 < nt) {
    a1A = *(const int4*)(pa0 + 3 * BK);  a1B = *(const int4*)(pa1 + 3 * BK);
    b1A = *(const int4*)(pb0 + 3 * BK);  b1B = *(const int4*)(pb1 + 3 * BK);
  }
  LDS_BARRIER();

  // phases 1..nt-2 in pairs (odd phase uses set0, even phase uses set1)
  for (int j = 1; j + 2 < nt; j += 2) {
    // phase j (odd): compute LDS1; write LDS0 <- set0 (tile j+1); issue t j+3
    compute(1);
    *(int4*)&As[0][l0] = a0A;  *(int4*)&As[0][l1] = a0B;
    *(int4*)&Bs[0][l0] = b0A;  *(int4*)&Bs[0][l1] = b0B;
    if (j + 3 < nt) {
      int k = (j + 3) * BK;
      a0A = *(const int4*)(pa0 + k);  a0B = *(const int4*)(pa1 + k);
      b0A = *(const int4*)(pb0 + k);  b0B = *(const int4*)(pb1 + k);
    }
    LDS_BARRIER();
    // phase j+1 (even): compute LDS0; write LDS1 <- set1 (tile j+2); issue t j+4
    compute(0);
    *(int4*)&As[1][l0] = a1A;  *(int4*)&As[1][l1] = a1B;
    *(int4*)&Bs[1][l0] = b1A;  *(int4*)&Bs[1][l1] = b1B;
    if (j + 4 < nt) {
      int k = (j + 4) * BK;
      a1A = *(const int4*)(pa0 + k);  a1B = *(const int4*)(pa1 + k);
      b1A = *(const int4*)(pb0 + k);  b1B = *(const int4*)(pb1 + k);
    }
    LDS_BARRIER();
  }

  // final phase nt-1 (odd since nt even): compute LDS1
  compute(1);

  // epilogue: D row = wm + mi*16 + quad*4 + r (M), col = wn + ni*16 + fr (N)
  float bv[4];
#pragma unroll
  for (int ni = 0; ni < 4; ++ni) bv[ni] = bb[tn * BN + wn + ni * 16 + fr];

#pragma unroll
  for (int mi = 0; mi < 4; ++mi) {
#pragma unroll
    for (int r = 0; r < 4; ++r) {
      int m = tm * BM + wm + mi * 16 + quad * 4 + r;
      int orow = m;
      if (OUT_MODE == 2) orow = perm[m];
#pragma unroll
      for (int ni = 0; ni < 4; ++ni) {
        int n = tn * BN + wn + ni * 16 + fr;
        float v = acc[mi][ni][r] + bv[ni];
        if (RELU) v = fmaxf(v, 0.f);
        if (OUT_MODE == 0) {
          ((unsigned short*)Cout)[(size_t)m * N + n] = f2bf(v);
        } else if (OUT_MODE == 1) {
          ((float*)Cout)[(size_t)m * N + n] = v;
        } else {
          if (orow >= 0) ((float*)Cout)[(size_t)orow * ldc + n] = v;
        }
      }
    }
  }
}

// ---------------- launch ----------------
extern "C" void kernel_launch(void* const* d_in, const int* in_sizes, int n_in,
                              void* d_out, int out_size, void* d_ws, size_t ws_size,
                              hipStream_t stream) {
  const float* x        = (const float*)d_in[0];
  const int*   labels   = (const int*)d_in[1];
  const float* eps      = (const float*)d_in[2];
  const float* W_enc0   = (const float*)d_in[3];
  const float* b_enc0   = (const float*)d_in[4];
  const float* W_enc1   = (const float*)d_in[5];
  const float* b_enc1   = (const float*)d_in[6];
  const float* W_mu     = (const float*)d_in[7];
  const float* b_mu     = (const float*)d_in[8];
  const float* W_logvar = (const float*)d_in[9];
  const float* b_logvar = (const float*)d_in[10];
  const float* W_dec0   = (const float*)d_in[11];
  const float* b_dec0   = (const float*)d_in[12];
  const float* W_dec1   = (const float*)d_in[13];
  const float* b_dec1   = (const float*)d_in[14];
  const float* W_out    = (const float*)d_in[15];
  const float* b_out    = (const float*)d_in[16];

  float* out_recon = (float*)d_out;
  float* out_mu    = out_recon + (size_t)B_ * DIN;
  float* out_lv    = out_mu + (size_t)B_ * LAT_;

  char* ws = (char*)d_ws;
  int* meta            = (int*)(ws + OFF_META);
  int* perm            = (int*)(ws + OFF_PERM);
  unsigned short* xg   = (unsigned short*)(ws + OFF_XG);
  unsigned short* h0   = (unsigned short*)(ws + OFF_H0);
  unsigned short* h1   = (unsigned short*)(ws + OFF_H1);
  float* mlp           = (float*)(ws + OFF_MLP);
  float* b_ml          = (float*)(ws + OFF_BML);
  unsigned short* Wt0  = (unsigned short*)(ws + OFF_WT0);
  unsigned short* Wt1  = (unsigned short*)(ws + OFF_WT1);
  unsigned short* Wml  = (unsigned short*)(ws + OFF_WML);
  unsigned short* Wd0  = (unsigned short*)(ws + OFF_WD0);
  unsigned short* Wd1  = (unsigned short*)(ws + OFF_WD1);
  unsigned short* Wout = (unsigned short*)(ws + OFF_WOUT);
  // buffer reuse (lifetimes disjoint):
  unsigned short* d1 = xg;   // [BP_CAP][H0]
  unsigned short* d0 = h0;   // [BP_CAP][H1]
  unsigned short* z  = h1;   // [BP_CAP][LAT]

  // fused conversion table (64k x 32n tiles)
  SegTable st;
  int ts = 0;
  auto seg = [&](int i, const float* s, unsigned short* d, int K, int N, int nb) {
    st.s[i] = SegDesc{s, d, K, N, nb, ts};
    ts += (K / 64) * (N / 32) * nb;
  };
  seg(0, W_enc0,   Wt0,                      DIN,  H0_,  NC);
  seg(1, W_enc1,   Wt1,                      H0_,  H1_,  1);
  seg(2, W_mu,     Wml,                      H1_,  LAT_, 1);
  seg(3, W_logvar, Wml + (size_t)LAT_ * H1_, H1_,  LAT_, 1);
  seg(4, W_dec0,   Wd0,                      LAT_, H1_,  1);
  seg(5, W_dec1,   Wd1,                      H1_,  H0_,  NC);
  seg(6, W_out,    Wout,                     H0_,  DIN,  1);

  setup_all<<<1, 1024, 0, stream>>>(labels, meta, perm, b_mu, b_logvar, b_ml);
  convert_all<<<ts, dim3(32, 8), 0, stream>>>(st);
  gather_x_kernel<<<dim3(BP_CAP, DIN / (256 * 4)), 256, 0, stream>>>(x, perm, xg);

  // enc0: [Bp,2048] @ Wt0[c][1024][2048] -> h0, relu
  gemm_kernel<0, true, true, true><<<TCAP * (H0_ / BN), 256, 0, stream>>>(
      xg, Wt0, b_enc0, h0, meta, perm, DIN, H0_, 0);
  // enc1: [Bp,1024] @ Wt1[512][1024] -> h1, relu
  gemm_kernel<0, true, false, false><<<TCAP * (H1_ / BN), 256, 0, stream>>>(
      h0, Wt1, b_enc1, h1, meta, perm, H0_, H1_, 0);
  // mu|logvar: [Bp,512] @ Wml[256][512] -> mlp (fp32)
  gemm_kernel<1, false, false, false><<<TCAP * (256 / BN), 256, 0, stream>>>(
      h1, Wml, b_ml, mlp, meta, perm, H1_, 256, 0);
  // reparameterize + scatter mu/logvar
  z_kernel<<<BP_CAP, 128, 0, stream>>>(mlp, eps, perm, z, out_mu, out_lv);
  // dec0: [Bp,128] @ Wd0[512][128] -> d0, relu
  gemm_kernel<0, true, false, false><<<TCAP * (H1_ / BN), 256, 0, stream>>>(
      z, Wd0, b_dec0, d0, meta, perm, LAT_, H1_, 0);
  // dec1: [Bp,512] @ Wd1[c][1024][512] -> d1, relu
  gemm_kernel<0, true, true, true><<<TCAP * (H0_ / BN), 256, 0, stream>>>(
      d0, Wd1, b_dec1, d1, meta, perm, H1_, H0_, 0);
  // out: [Bp,1024] @ Wout[2048][1024] -> scatter fp32 recon
  gemm_kernel<2, false, false, false><<<TCAP * (DIN / BN), 256, 0, stream>>>(
      d1, Wout, b_out, out_recon, meta, perm, H0_, DIN, DIN);

  (void)in_sizes; (void)n_in; (void)out_size; (void)ws_size;
}